// Round 2
// baseline (85460.486 us; speedup 1.0000x reference)
//
#include <hip/hip_runtime.h>
#include <math.h>

// ESN recurrence: x_t = tanh(w_in*u_t + W x_{t-1}); out[t-washout] = c . x_t
// R2: W resident in LDS (fence-immune), two-level grid barrier (spread arrival
// counters -> master -> replicated epoch flags), readout via spread part-slots
// reduced by an epilogue kernel, u prefetched one step ahead.

#define H_   2048
#define RPB  8          // rows per block
#define NBLK 256
// ws float layout:
//   [0,2048)      xbuf0
//   [2048,4096)   xbuf1
//   [4096,6144)   c (readout coefficients, scatter of w_out by mask)
//   uint [6144..6400)  arrival counters: 8 lines, stride 32 uints (128 B)
//   uint [6400..6656)  epoch flags:      8 lines, stride 32 uints
//   [8192, 8192+T*32)  part accumulators: 32 spread slots per step

__global__ void esn_zero(float* __restrict__ ws_f, int n)
{
    int i = blockIdx.x * blockDim.x + threadIdx.x;
    int stride = gridDim.x * blockDim.x;
    for (; i < n; i += stride) ws_f[i] = 0.0f;
}

__global__ __launch_bounds__(1024) void esn_scatter_c(const int* __restrict__ mask,
                                                      const float* __restrict__ w_out,
                                                      float* __restrict__ ws_f, int H)
{
    float* c = ws_f + 2 * H_;
    for (int i = threadIdx.x; i < H; i += blockDim.x)
        atomicAdd(&c[mask[i]], w_out[i]);
}

__global__ __launch_bounds__(256) void esn_run(const float* __restrict__ u,
                                               const float* __restrict__ w_res,
                                               const float* __restrict__ w_in,
                                               float* __restrict__ out,
                                               float* __restrict__ ws_f,
                                               int T, int washout, int use_part)
{
    __shared__ float Wlds[RPB * H_];   // exactly 64 KB

    const int tid  = threadIdx.x;
    const int wave = tid >> 6;
    const int lane = tid & 63;
    const int bid  = blockIdx.x;
    const int r0 = 2 * wave, r1 = 2 * wave + 1;
    const int grow0 = bid * RPB + r0, grow1 = bid * RPB + r1;

    // ---- one-time: stage this block's 8 W rows into LDS (coalesced) ----
    {
        const float4* src = (const float4*)(w_res + (size_t)bid * RPB * H_);
        float4* dst = (float4*)Wlds;
        for (int i = tid; i < RPB * H_ / 4; i += 256) dst[i] = src[i];
    }
    float win0 = 0.f, win1 = 0.f, c0 = 0.f, c1 = 0.f;
    if (lane == 0) {
        win0 = w_in[grow0]; win1 = w_in[grow1];
        c0 = ws_f[2 * H_ + grow0]; c1 = ws_f[2 * H_ + grow1];
    }
    __syncthreads();

    float* buf0 = ws_f;
    float* buf1 = ws_f + H_;
    unsigned* counters = (unsigned*)(ws_f + 6144);
    unsigned* flags    = (unsigned*)(ws_f + 6400);
    unsigned* mycnt  = counters + (bid & 7) * 32;
    unsigned* myflag = flags    + (bid & 7) * 32;
    float* part = ws_f + 8192;
    const int pg = (bid & 7) * 4 + wave;   // 32 spread part slots per step

    const float4* w0p = (const float4*)(Wlds + r0 * H_);
    const float4* w1p = (const float4*)(Wlds + r1 * H_);

    int broken = 0;
    float u_next = u[0];   // whole-wave same-addr load; u is immutable

    for (int k = 0; k < T; ++k) {
        const float4* xg = (const float4*)((k & 1) ? buf1 : buf0);
        float*       xdst = (k & 1) ? buf0 : buf1;
        float uk = u_next;
        if (k + 1 < T) u_next = u[k + 1];   // prefetch; latency hidden by barrier

        // ---- dot: wave owns rows r0,r1; lanes sweep 2048 as float4 ----
        float4 a0 = {0.f, 0.f, 0.f, 0.f}, a1 = {0.f, 0.f, 0.f, 0.f};
#pragma unroll
        for (int c = 0; c < 8; ++c) {
            float4 xv  = xg[c * 64 + lane];     // coalesced 1 KB/wave from L3
            float4 wv0 = w0p[c * 64 + lane];    // conflict-free ds_read_b128
            float4 wv1 = w1p[c * 64 + lane];
            a0.x = fmaf(wv0.x, xv.x, a0.x); a0.y = fmaf(wv0.y, xv.y, a0.y);
            a0.z = fmaf(wv0.z, xv.z, a0.z); a0.w = fmaf(wv0.w, xv.w, a0.w);
            a1.x = fmaf(wv1.x, xv.x, a1.x); a1.y = fmaf(wv1.y, xv.y, a1.y);
            a1.z = fmaf(wv1.z, xv.z, a1.z); a1.w = fmaf(wv1.w, xv.w, a1.w);
        }
        float s0 = (a0.x + a0.y) + (a0.z + a0.w);
        float s1 = (a1.x + a1.y) + (a1.z + a1.w);
#pragma unroll
        for (int d = 1; d < 64; d <<= 1) {
            s0 += __shfl_xor(s0, d);
            s1 += __shfl_xor(s1, d);
        }

        float pw = 0.f;
        if (lane == 0) {
            float z0 = fmaf(win0, uk, s0);
            float z1 = fmaf(win1, uk, s1);
            z0 = fminf(fmaxf(z0, -15.f), 15.f);
            z1 = fminf(fmaxf(z1, -15.f), 15.f);
            float e0 = __expf(2.f * z0), e1 = __expf(2.f * z1);
            float t0 = (e0 - 1.f) / (e0 + 1.f), t1 = (e1 - 1.f) / (e1 + 1.f);
            xdst[grow0] = t0;
            xdst[grow1] = t1;
            pw = c0 * t0 + c1 * t1;
        }
        __syncthreads();   // drains all waves' x-stores (vmcnt 0 before s_barrier)

        // ---- arrival: release then add (wave 0) ----
        if (wave == 0) {
            __builtin_amdgcn_fence(__ATOMIC_RELEASE, "agent");
            if (lane == 0)
                __hip_atomic_fetch_add(mycnt, 1u, __ATOMIC_RELAXED, __HIP_MEMORY_SCOPE_AGENT);
        }
        // ---- readout partial: AFTER arrival add -> off the critical path ----
        if (lane == 0 && k >= washout) {
            if (use_part) atomicAdd(&part[(size_t)k * 32 + pg], pw);
            else          atomicAdd(&out[k - washout], pw);
        }

        // ---- two-level barrier ----
        if (bid == 0) {
            if (wave == 0 && !broken) {
                unsigned target = (unsigned)(k + 1) * 32u;  // 32 blocks per counter
                int spins = 0;
                for (;;) {
                    unsigned v = target;
                    if (lane < 8)
                        v = __hip_atomic_load(counters + lane * 32, __ATOMIC_RELAXED,
                                              __HIP_MEMORY_SCOPE_AGENT);
                    if (__all(v >= target)) break;
                    if (++spins > 40000000) { broken = 1; break; }
                }
            }
            if (wave == 0 && lane < 8)   // publish epoch (producers' data already at L3)
                __hip_atomic_store(flags + lane * 32, (unsigned)(k + 1),
                                   __ATOMIC_RELAXED, __HIP_MEMORY_SCOPE_AGENT);
        } else {
            if (wave == 0 && !broken) {
                unsigned target = (unsigned)(k + 1);
                int spins = 0;
                for (;;) {
                    unsigned v = __hip_atomic_load(myflag, __ATOMIC_RELAXED,
                                                   __HIP_MEMORY_SCOPE_AGENT);
                    if (v >= target) break;
                    if (++spins > 40000000) { broken = 1; break; }
                }
            }
        }
        if (wave == 0) __builtin_amdgcn_fence(__ATOMIC_ACQUIRE, "agent");
        __syncthreads();
    }
}

__global__ void esn_reduce(const float* __restrict__ part, float* __restrict__ out,
                           int out_size, int washout)
{
    int t = blockIdx.x * blockDim.x + threadIdx.x;
    if (t >= out_size) return;
    const float* p = part + (size_t)(t + washout) * 32;
    float s = 0.f;
#pragma unroll
    for (int g = 0; g < 32; ++g) s += p[g];
    out[t] = s;
}

extern "C" void kernel_launch(void* const* d_in, const int* in_sizes, int n_in,
                              void* d_out, int out_size, void* d_ws, size_t ws_size,
                              hipStream_t stream)
{
    const float* u     = (const float*)d_in[0];
    const float* w_res = (const float*)d_in[1];
    const float* w_in  = (const float*)d_in[2];
    const float* w_out = (const float*)d_in[3];
    const int*   mask  = (const int*)d_in[4];
    int T = in_sizes[0];
    int H = in_sizes[2];
    int washout = T - out_size;
    float* out  = (float*)d_out;
    float* ws_f = (float*)d_ws;

    size_t need = (size_t)(8192 + (size_t)T * 32) * 4;
    int use_part = (ws_size >= need) ? 1 : 0;
    int zero_n = use_part ? (8192 + T * 32) : 8192;

    hipLaunchKernelGGL(esn_zero, dim3(64), dim3(256), 0, stream, ws_f, zero_n);
    if (!use_part)   // direct-atomic fallback needs out pre-zeroed
        hipLaunchKernelGGL(esn_zero, dim3(32), dim3(256), 0, stream, out, out_size);
    hipLaunchKernelGGL(esn_scatter_c, dim3(1), dim3(1024), 0, stream, mask, w_out, ws_f, H);

    void* args[] = { (void*)&u, (void*)&w_res, (void*)&w_in, (void*)&out,
                     (void*)&ws_f, (void*)&T, (void*)&washout, (void*)&use_part };
    hipError_t e = hipLaunchCooperativeKernel((const void*)esn_run,
                                              dim3(NBLK), dim3(256),
                                              args, 0, stream);
    if (e != hipSuccess) {
        hipLaunchKernelGGL(esn_run, dim3(NBLK), dim3(256), 0, stream,
                           u, w_res, w_in, out, ws_f, T, washout, use_part);
    }
    if (use_part)
        hipLaunchKernelGGL(esn_reduce, dim3((out_size + 255) / 256), dim3(256), 0, stream,
                           ws_f + 8192, out, out_size, washout);
}

// Round 3
// 78276.971 us; speedup vs baseline: 1.0918x; 1.0918x over previous
//
#include <hip/hip_runtime.h>
#include <math.h>

// ESN recurrence: x_t = tanh(w_in*u_t + W x_{t-1}); out[t-washout] = c . x_t
// R3: ZERO fences in the step loop. All cross-block traffic (x, counters) uses
// agent-scope relaxed atomics (sc0/sc1 -> served at L3, bypassing the
// non-coherent per-XCD L2s). R1/R2's per-step agent fences compiled to bulk
// buffer_wbl2 / buffer_inv (L2 writeback+invalidate) -- that was the ~10us/step.
// W stays in LDS; x is staged to LDS once per block per step.

#define H_   2048
#define RPB  8          // rows per block
#define NBLK 256
// ws float layout:
//   [0,2048)      xbuf0
//   [2048,4096)   xbuf1
//   [4096,6144)   c (readout coefficients, scatter of w_out by mask)
//   uint [6144,7168)   arrival counters: 32 lines, stride 32 uints (128 B)
//   [8192, 8192+T*32)  part accumulators: 32 spread slots per step

__global__ void esn_zero(float* __restrict__ ws_f, int n)
{
    int i = blockIdx.x * blockDim.x + threadIdx.x;
    int stride = gridDim.x * blockDim.x;
    for (; i < n; i += stride) ws_f[i] = 0.0f;
}

__global__ __launch_bounds__(1024) void esn_scatter_c(const int* __restrict__ mask,
                                                      const float* __restrict__ w_out,
                                                      float* __restrict__ ws_f, int H)
{
    float* c = ws_f + 2 * H_;
    for (int i = threadIdx.x; i < H; i += blockDim.x)
        atomicAdd(&c[mask[i]], w_out[i]);
}

__global__ __launch_bounds__(256) void esn_run(const float* __restrict__ u,
                                               const float* __restrict__ w_res,
                                               const float* __restrict__ w_in,
                                               float* __restrict__ out,
                                               float* __restrict__ ws_f,
                                               int T, int washout, int use_part)
{
    __shared__ float Wlds[RPB * H_];   // 64 KB
    __shared__ float xs[H_];           // 8 KB staged x_{t-1}

    const int tid  = threadIdx.x;
    const int wave = tid >> 6;
    const int lane = tid & 63;
    const int bid  = blockIdx.x;
    const int r0 = 2 * wave, r1 = 2 * wave + 1;
    const int grow0 = bid * RPB + r0, grow1 = bid * RPB + r1;

    // ---- one-time: stage this block's 8 W rows into LDS (coalesced) ----
    {
        const float4* src = (const float4*)(w_res + (size_t)bid * RPB * H_);
        float4* dst = (float4*)Wlds;
        for (int i = tid; i < RPB * H_ / 4; i += 256) dst[i] = src[i];
    }
    float win0 = 0.f, win1 = 0.f, c0 = 0.f, c1 = 0.f;
    if (lane == 0) {
        win0 = w_in[grow0]; win1 = w_in[grow1];
        c0 = ws_f[2 * H_ + grow0]; c1 = ws_f[2 * H_ + grow1];
    }

    float* buf0 = ws_f;
    float* buf1 = ws_f + H_;
    unsigned* counters = (unsigned*)(ws_f + 6144);
    unsigned* mycnt = counters + (bid & 31) * 32;  // 32 lines, 8 blocks each
    float* part = ws_f + 8192;
    const int pg = (bid & 7) * 4 + wave;           // 32 spread part slots/step

    const float4* w0p = (const float4*)(Wlds + r0 * H_);
    const float4* w1p = (const float4*)(Wlds + r1 * H_);
    const float4* xs4 = (const float4*)xs;

    int broken = 0;
    float u_next = u[0];
    __syncthreads();   // Wlds ready

    for (int k = 0; k < T; ++k) {
        // ---- stage x_{t-1} from L3 into LDS (agent-scope relaxed loads) ----
        const float* xsrc = (k & 1) ? buf1 : buf0;
        float*       xdst = (k & 1) ? buf0 : buf1;
#pragma unroll
        for (int i = 0; i < 8; ++i) {
            int j = (i << 8) + tid;
            xs[j] = __hip_atomic_load(xsrc + j, __ATOMIC_RELAXED,
                                      __HIP_MEMORY_SCOPE_AGENT);
        }
        float uk = u_next;
        if (k + 1 < T) u_next = u[k + 1];   // L2-cached now (no invalidates)
        __syncthreads();

        // ---- dot: wave owns rows r0,r1; lanes sweep 2048 as float4 ----
        float4 a0 = {0.f, 0.f, 0.f, 0.f}, a1 = {0.f, 0.f, 0.f, 0.f};
#pragma unroll
        for (int c = 0; c < 8; ++c) {
            float4 xv  = xs4[c * 64 + lane];
            float4 wv0 = w0p[c * 64 + lane];
            float4 wv1 = w1p[c * 64 + lane];
            a0.x = fmaf(wv0.x, xv.x, a0.x); a0.y = fmaf(wv0.y, xv.y, a0.y);
            a0.z = fmaf(wv0.z, xv.z, a0.z); a0.w = fmaf(wv0.w, xv.w, a0.w);
            a1.x = fmaf(wv1.x, xv.x, a1.x); a1.y = fmaf(wv1.y, xv.y, a1.y);
            a1.z = fmaf(wv1.z, xv.z, a1.z); a1.w = fmaf(wv1.w, xv.w, a1.w);
        }
        float s0 = (a0.x + a0.y) + (a0.z + a0.w);
        float s1 = (a1.x + a1.y) + (a1.z + a1.w);
#pragma unroll
        for (int d = 1; d < 64; d <<= 1) {
            s0 += __shfl_xor(s0, d);
            s1 += __shfl_xor(s1, d);
        }

        float pw = 0.f;
        if (lane == 0) {
            float z0 = fmaf(win0, uk, s0);
            float z1 = fmaf(win1, uk, s1);
            z0 = fminf(fmaxf(z0, -15.f), 15.f);
            z1 = fminf(fmaxf(z1, -15.f), 15.f);
            float e0 = __expf(2.f * z0), e1 = __expf(2.f * z1);
            float t0 = (e0 - 1.f) / (e0 + 1.f), t1 = (e1 - 1.f) / (e1 + 1.f);
            // write-through to L3: visible to all XCDs once vmcnt drains
            __hip_atomic_store(xdst + grow0, t0, __ATOMIC_RELAXED,
                               __HIP_MEMORY_SCOPE_AGENT);
            __hip_atomic_store(xdst + grow1, t1, __ATOMIC_RELAXED,
                               __HIP_MEMORY_SCOPE_AGENT);
            pw = c0 * t0 + c1 * t1;
        }
        asm volatile("s_waitcnt vmcnt(0)" ::: "memory");  // x stores at L3
        __syncthreads();                                   // all waves drained

        // ---- arrival (no fence: stores already at coherence point) ----
        if (wave == 0 && lane == 0)
            __hip_atomic_fetch_add(mycnt, 1u, __ATOMIC_RELAXED,
                                   __HIP_MEMORY_SCOPE_AGENT);
        // readout partial: fire-and-forget, off the critical path
        if (lane == 0 && k >= washout) {
            if (use_part) atomicAdd(&part[(size_t)k * 32 + pg], pw);
            else          atomicAdd(&out[k - washout], pw);
        }

        // ---- poll all 32 counters (one vector load + __all) ----
        if (wave == 0 && !broken) {
            unsigned target = (unsigned)(k + 1) * 8u;   // 8 blocks per counter
            int spins = 0;
            for (;;) {
                unsigned v = target;
                if (lane < 32)
                    v = __hip_atomic_load(counters + lane * 32, __ATOMIC_RELAXED,
                                          __HIP_MEMORY_SCOPE_AGENT);
                if (__all(v >= target)) break;
                if (++spins > 2000000) { broken = 1; break; }
            }
        }
        __syncthreads();
    }
}

__global__ void esn_reduce(const float* __restrict__ part, float* __restrict__ out,
                           int out_size, int washout)
{
    int t = blockIdx.x * blockDim.x + threadIdx.x;
    if (t >= out_size) return;
    const float* p = part + (size_t)(t + washout) * 32;
    float s = 0.f;
#pragma unroll
    for (int g = 0; g < 32; ++g) s += p[g];
    out[t] = s;
}

extern "C" void kernel_launch(void* const* d_in, const int* in_sizes, int n_in,
                              void* d_out, int out_size, void* d_ws, size_t ws_size,
                              hipStream_t stream)
{
    const float* u     = (const float*)d_in[0];
    const float* w_res = (const float*)d_in[1];
    const float* w_in  = (const float*)d_in[2];
    const float* w_out = (const float*)d_in[3];
    const int*   mask  = (const int*)d_in[4];
    int T = in_sizes[0];
    int H = in_sizes[2];
    int washout = T - out_size;
    float* out  = (float*)d_out;
    float* ws_f = (float*)d_ws;

    size_t need = (size_t)(8192 + (size_t)T * 32) * 4;
    int use_part = (ws_size >= need) ? 1 : 0;
    int zero_n = use_part ? (8192 + T * 32) : 8192;

    hipLaunchKernelGGL(esn_zero, dim3(64), dim3(256), 0, stream, ws_f, zero_n);
    if (!use_part)
        hipLaunchKernelGGL(esn_zero, dim3(32), dim3(256), 0, stream, out, out_size);
    hipLaunchKernelGGL(esn_scatter_c, dim3(1), dim3(1024), 0, stream, mask, w_out, ws_f, H);

    void* args[] = { (void*)&u, (void*)&w_res, (void*)&w_in, (void*)&out,
                     (void*)&ws_f, (void*)&T, (void*)&washout, (void*)&use_part };
    hipError_t e = hipLaunchCooperativeKernel((const void*)esn_run,
                                              dim3(NBLK), dim3(256),
                                              args, 0, stream);
    if (e != hipSuccess) {
        hipLaunchKernelGGL(esn_run, dim3(NBLK), dim3(256), 0, stream,
                           u, w_res, w_in, out, ws_f, T, washout, use_part);
    }
    if (use_part)
        hipLaunchKernelGGL(esn_reduce, dim3((out_size + 255) / 256), dim3(256), 0, stream,
                           ws_f + 8192, out, out_size, washout);
}